// Round 8
// baseline (531.348 us; speedup 1.0000x reference)
//
#include <hip/hip_runtime.h>
#include <hip/hip_bf16.h>
#include <stdint.h>
#include <stddef.h>

// Problem constants (from reference setup_inputs)
#define N_NODES 8192
#define DIM     256
#define BATCH   4096
#define CLASSES 1000
#define ALPHA_C 1.0f
#define BETA_C  0.01f
#define GAMMA_C 0.1f

// mean(adj*(1-sim)) = (Sum[a] - <A*U, U>)/N^2, U = row-normalized embeddings.
//
// R8: DECOUPLE the adj stream from the GEMM.
//  k1 stream_cvt: memcpy-shaped linear read of adj (268 MB) + bf16 cvt ->
//     Abf (134 MB) + Sum[a], Sum[|a|].  (diagnoses raw read BW)
//  k2 gemm: W = Abf*U on bf16 A (half traffic, L3-warm), R5 structure,
//     40 KB LDS -> 4 blocks/CU, 16 waves/CU.
#define KSPLIT  16
#define KRANGE  (N_NODES / KSPLIT)   // 512
#define NBK     (KRANGE / 64)        // 8
#define BM      64

typedef __bf16 bf16_t;
typedef __bf16 bf16x8 __attribute__((ext_vector_type(8)));
typedef float  f32x16 __attribute__((ext_vector_type(16)));

// Async global->LDS DMA, 16 B/lane, dest = wave-uniform base + lane*16.
__device__ __forceinline__ void async16(const void* g, void* l) {
  __builtin_amdgcn_global_load_lds(
      (const __attribute__((address_space(1))) uint32_t*)g,
      (__attribute__((address_space(3))) uint32_t*)l, 16, 0, 0);
}

// ---------------------------------------------------------------------------
// prep_norm: L2-normalize each embedding row (fp32 math), store U bf16.
// ---------------------------------------------------------------------------
__global__ __launch_bounds__(256) void prep_norm(
    const float* __restrict__ emb, bf16_t* __restrict__ U) {
  const int row = blockIdx.x;
  const int t = threadIdx.x;
  const float v = emb[(size_t)row * DIM + t];
  float sq = v * v;
  for (int off = 32; off; off >>= 1) sq += __shfl_down(sq, off);
  __shared__ float red[4];
  if ((t & 63) == 0) red[t >> 6] = sq;
  __syncthreads();
  const float total = red[0] + red[1] + red[2] + red[3];
  U[(size_t)row * DIM + t] = (bf16_t)(v * rsqrtf(total));
}

// ---------------------------------------------------------------------------
// prep_transpose: V = U^T via 64x64 LDS tiles, 16 B coalesced both sides.
// ---------------------------------------------------------------------------
#define TP 68  // padded LDS row stride (bf16 elems)

__global__ __launch_bounds__(256) void prep_transpose(
    const bf16_t* __restrict__ U, bf16_t* __restrict__ V) {
  __shared__ bf16_t tile[64 * TP];
  const int k0 = blockIdx.x * 64;  // node block
  const int d0 = blockIdx.y * 64;  // dim block
  const int t = threadIdx.x;
  const int r = t >> 3;            // 0..31
  const int c8 = t & 7;            // 16B chunk

  *(bf16x8*)&tile[r * TP + c8 * 8] =
      *(const bf16x8*)&U[(size_t)(k0 + r) * DIM + d0 + c8 * 8];
  *(bf16x8*)&tile[(r + 32) * TP + c8 * 8] =
      *(const bf16x8*)&U[(size_t)(k0 + r + 32) * DIM + d0 + c8 * 8];
  __syncthreads();

  bf16x8 o0, o1;
#pragma unroll
  for (int j = 0; j < 8; ++j) {
    o0[j] = tile[(c8 * 8 + j) * TP + r];
    o1[j] = tile[(c8 * 8 + j) * TP + r + 32];
  }
  *(bf16x8*)&V[(size_t)(d0 + r) * N_NODES + k0 + c8 * 8] = o0;
  *(bf16x8*)&V[(size_t)(d0 + r + 32) * N_NODES + k0 + c8 * 8] = o1;
}

// ---------------------------------------------------------------------------
// Cross-entropy: one block per batch row; single global pass, logits in regs.
// ---------------------------------------------------------------------------
__global__ __launch_bounds__(256) void ce_kernel(
    const float* __restrict__ pred, const int* __restrict__ target,
    float* __restrict__ out) {
  const int row = blockIdx.x;
  const int t = threadIdx.x;
  const float* p = pred + (size_t)row * CLASSES;

  float v[4];
  for (int k = 0; k < 4; ++k) {
    const int c = t + k * 256;
    v[k] = (c < CLASSES) ? p[c] : -INFINITY;
  }

  float m = fmaxf(fmaxf(v[0], v[1]), fmaxf(v[2], v[3]));
  for (int off = 32; off; off >>= 1) m = fmaxf(m, __shfl_down(m, off));

  __shared__ float red[8];
  const int wave = t >> 6, lane = t & 63;
  if (lane == 0) red[wave] = m;
  __syncthreads();
  if (t == 0) red[4] = fmaxf(fmaxf(red[0], red[1]), fmaxf(red[2], red[3]));
  __syncthreads();
  const float mx = red[4];

  float s = 0.f;
  for (int k = 0; k < 4; ++k) s += __expf(v[k] - mx);
  for (int off = 32; off; off >>= 1) s += __shfl_down(s, off);
  if (lane == 0) red[wave] = s;
  __syncthreads();
  if (t == 0) {
    float ssum = red[0] + red[1] + red[2] + red[3];
    float lse = mx + __logf(ssum);
    float loss = lse - p[target[row]];
    atomicAdd(out, loss * (ALPHA_C / (float)BATCH));
  }
}

// ---------------------------------------------------------------------------
// stream_cvt: memcpy-shaped. Each thread handles 8 pairs of float4 (32 B/lane
// per step, whole wave = 2 KB contiguous), cvt -> bf16x8 linear store
// (16 B/lane, 1 KB/wave), accumulate Sum[a], Sum[|a|].
// Adds (BETA*Sum|a| + GAMMA*Sum[a])/N^2 to out. 67.1M floats total.
// ---------------------------------------------------------------------------
#define SBLK 4096

__global__ __launch_bounds__(256, 8) void stream_cvt(
    const float* __restrict__ adj, bf16_t* __restrict__ Abf,
    float* __restrict__ out) {
  const int gi = blockIdx.x * 256 + threadIdx.x;  // 0..1048575
  float sa = 0.f, sabs = 0.f;

#pragma unroll
  for (int it = 0; it < 8; ++it) {
    const size_t P = (size_t)it * (SBLK * 256) + gi;  // pair index
    const float4 v0 = *(const float4*)(adj + P * 8);
    const float4 v1 = *(const float4*)(adj + P * 8 + 4);
    sa += v0.x + v0.y + v0.z + v0.w + v1.x + v1.y + v1.z + v1.w;
    sabs += fabsf(v0.x) + fabsf(v0.y) + fabsf(v0.z) + fabsf(v0.w) +
            fabsf(v1.x) + fabsf(v1.y) + fabsf(v1.z) + fabsf(v1.w);
    bf16x8 c;
    c[0] = (bf16_t)v0.x; c[1] = (bf16_t)v0.y;
    c[2] = (bf16_t)v0.z; c[3] = (bf16_t)v0.w;
    c[4] = (bf16_t)v1.x; c[5] = (bf16_t)v1.y;
    c[6] = (bf16_t)v1.z; c[7] = (bf16_t)v1.w;
    *(bf16x8*)(Abf + P * 8) = c;
  }

  float local = BETA_C * sabs + GAMMA_C * sa;
  for (int off = 32; off; off >>= 1) local += __shfl_down(local, off);
  __shared__ float red[4];
  if ((threadIdx.x & 63) == 0) red[threadIdx.x >> 6] = local;
  __syncthreads();
  if (threadIdx.x == 0) {
    const float inv = 1.f / ((float)N_NODES * (float)N_NODES);
    atomicAdd(out, (red[0] + red[1] + red[2] + red[3]) * inv);
  }
}

// ---------------------------------------------------------------------------
// gemm: W = Abf * U (BM=64 rows x D=256, K-split 16), epilogue <W,U>.
// As[64][64] bf16 (8 KB) staged via 8 async16/block (2 per wave), XOR swizzle
// (16B chunk c of row r at c^(r&7)). Bs[256][64] (32 KB): wave w DMAs its own
// 64-d slice. 40 KB LDS -> 4 blocks/CU; VGPR<=128 -> 16 waves/CU.
// Wave w: d-cols [w*64,w*64+64) x 64 rows = 2x2 v_mfma_f32_32x32x16_bf16.
// Adds -GAMMA*<W,U>/N^2 to out.
// ---------------------------------------------------------------------------
__global__ __launch_bounds__(256, 4) void gemm_kernel(
    const bf16_t* __restrict__ Abf, const bf16_t* __restrict__ U,
    const bf16_t* __restrict__ V, float* __restrict__ out) {
  __shared__ __align__(16) bf16_t As[BM * 64];    // 8 KB
  __shared__ __align__(16) bf16_t Bs[DIM * 64];   // 32 KB
  __shared__ float red[4];

  const int i0 = blockIdx.x * BM;
  const int kbase = blockIdx.y * KRANGE;
  const int t = threadIdx.x;
  const int w = t >> 6, lane = t & 63;
  const int m = lane & 31, h = lane >> 5;
  const int srow = lane >> 3;                 // 0..7
  const int sch = (lane & 7) ^ srow;          // swizzled chunk fetch

  f32x16 acc[2][2] = {};

  for (int bk = 0; bk < NBK; ++bk) {
    const int k0 = kbase + bk * 64;

    // A: 2 async16 per wave -> 16 rows (wave w rows w*16..w*16+15).
#pragma unroll
    for (int q = 0; q < 2; ++q) {
      const int rbase = w * 16 + q * 8;  // wave-uniform
      async16(Abf + (size_t)(i0 + rbase + srow) * N_NODES + k0 + sch * 8,
              &As[rbase * 64]);
    }
    // B: wave w stages its own d-slice (8 async16).
#pragma unroll
    for (int q = 0; q < 8; ++q) {
      const int dbase = w * 64 + q * 8;  // wave-uniform
      async16(V + (size_t)(dbase + srow) * N_NODES + k0 + sch * 8,
              &Bs[dbase * 64]);
    }
    __syncthreads();

#pragma unroll
    for (int kk = 0; kk < 4; ++kk) {
      const int p = ((kk * 2 + h) ^ (m & 7)) * 8;  // deswizzle
      bf16x8 a0 = *(const bf16x8*)&As[m * 64 + p];
      bf16x8 a1 = *(const bf16x8*)&As[(m + 32) * 64 + p];
      bf16x8 b0 = *(const bf16x8*)&Bs[(w * 64 + m) * 64 + p];
      bf16x8 b1 = *(const bf16x8*)&Bs[(w * 64 + 32 + m) * 64 + p];
      acc[0][0] = __builtin_amdgcn_mfma_f32_32x32x16_bf16(a0, b0, acc[0][0],
                                                          0, 0, 0);
      acc[0][1] = __builtin_amdgcn_mfma_f32_32x32x16_bf16(a0, b1, acc[0][1],
                                                          0, 0, 0);
      acc[1][0] = __builtin_amdgcn_mfma_f32_32x32x16_bf16(a1, b0, acc[1][0],
                                                          0, 0, 0);
      acc[1][1] = __builtin_amdgcn_mfma_f32_32x32x16_bf16(a1, b1, acc[1][1],
                                                          0, 0, 0);
    }
    __syncthreads();
  }

  // Epilogue: simdot = <acc, U-tile>. C/D (32x32): col = lane&31 (d),
  // row = (reg&3) + 8*(reg>>2) + 4*(lane>>5) (i).
  float simdot = 0.f;
#pragma unroll
  for (int mi = 0; mi < 2; ++mi) {
#pragma unroll
    for (int nd = 0; nd < 2; ++nd) {
      const int ib = i0 + mi * 32 + 4 * h;
      const int d = w * 64 + nd * 32 + m;
      const bf16_t* up = U + (size_t)ib * DIM + d;
#pragma unroll
      for (int rg = 0; rg < 16; ++rg) {
        const int row = (rg & 3) + 8 * (rg >> 2);
        simdot += (float)up[(size_t)row * DIM] * acc[mi][nd][rg];
      }
    }
  }

  float local = -GAMMA_C * simdot;
  for (int off = 32; off; off >>= 1) local += __shfl_down(local, off);
  if (lane == 0) red[w] = local;
  __syncthreads();
  if (t == 0) {
    const float inv = 1.f / ((float)N_NODES * (float)N_NODES);
    atomicAdd(out, (red[0] + red[1] + red[2] + red[3]) * inv);
  }
}

// ---------------------------------------------------------------------------
extern "C" void kernel_launch(void* const* d_in, const int* in_sizes, int n_in,
                              void* d_out, int out_size, void* d_ws,
                              size_t ws_size, hipStream_t stream) {
  const float* pred   = (const float*)d_in[0];
  const int*   target = (const int*)d_in[1];
  const float* adj    = (const float*)d_in[2];
  const float* emb    = (const float*)d_in[3];
  float* out = (float*)d_out;

  bf16_t* U   = (bf16_t*)d_ws;                                        // 4 MB
  bf16_t* V   = (bf16_t*)((char*)d_ws + (size_t)4 * 1024 * 1024);     // 4 MB
  bf16_t* Abf = (bf16_t*)((char*)d_ws + (size_t)8 * 1024 * 1024);     // 134 MB

  hipMemsetAsync(d_out, 0, sizeof(float), stream);
  ce_kernel<<<BATCH, 256, 0, stream>>>(pred, target, out);
  prep_norm<<<N_NODES, 256, 0, stream>>>(emb, U);
  prep_transpose<<<dim3(N_NODES / 64, DIM / 64), 256, 0, stream>>>(U, V);
  stream_cvt<<<SBLK, 256, 0, stream>>>(adj, Abf, out);
  gemm_kernel<<<dim3(N_NODES / BM, KSPLIT), 256, 0, stream>>>(Abf, U, V, out);
}